// Round 3
// baseline (290.981 us; speedup 1.0000x reference)
//
#include <hip/hip_runtime.h>

// CovarianceLayer: out = boxmean5x5( (center(x)-boxmean5x5(x)) * (center(y)-boxmean5x5(y)) )
// x,y: [16,1,1024,1024] fp32; out: [16,1,1016,1016] fp32.
//
// Register-resident vertical scan (no LDS, no barriers). R3 changes vs R2:
//  - RCHUNK 32 -> 16: 5120 wave-jobs = 20 waves/CU (was 10) -> 2x latency hiding.
//    Read amplification 1.25x -> 1.5x, but halo re-reads hit L2/L3 (inputs are
//    L3-resident at 128 MB < 256 MB).
//  - explicit next-row prefetch (xn1/yn1) so each wave keeps +2 loads in flight
//    across the unrolled step boundary.

#define W 1024
#define H 1024
#define OW 1016
#define OH 1016
#define NBATCH 16
#define NSTRIP 5
#define NCHUNK 64
#define RCHUNK 16
#define NSTEP (RCHUNK + 8)    // 24 input rows per job
#define STRIP_OUT 248

__device__ __forceinline__ float shfl_up1(float v) { return __shfl_up(v, 1, 64); }
__device__ __forceinline__ float shfl_dn1(float v) { return __shfl_down(v, 1, 64); }

__global__ __launch_bounds__(256) void cov_kernel(
    const float* __restrict__ x, const float* __restrict__ y,
    float* __restrict__ out)
{
    const int wid  = (blockIdx.x << 2) + (threadIdx.x >> 6);
    const int lane = threadIdx.x & 63;

    // job decode: chunk fastest (adjacent waves share row halo in cache)
    const int chunk = wid & (NCHUNK - 1);
    const int rest  = wid >> 6;
    const int strip = rest % NSTRIP;
    const int batch = rest / NSTRIP;

    const int o0   = chunk * RCHUNK;      // first output row of this job
    const int base = strip * STRIP_OUT;   // first input col of this strip

    int col4 = base + (lane << 2);
    if (col4 > W - 4) col4 = W - 4;       // clamp (strip 4 tail lanes; masked below)

    const float* __restrict__ xb = x + (size_t)batch * H * W;
    const float* __restrict__ yb = y + (size_t)batch * H * W;
    float* __restrict__ ob = out + (size_t)batch * OH * OW;

    const int j4 = base + ((lane - 1) << 2);   // first output col this lane stores
    const bool lane_ok = (lane >= 1) && (lane <= 62) && (j4 <= OW - 4);

    constexpr float inv25 = 1.0f / 25.0f;

    float4 xr[5], yr[5], pr[5];
    float4 vx = make_float4(0.f, 0.f, 0.f, 0.f);
    float4 vy = vx, vp = vx;
    #pragma unroll
    for (int u = 0; u < 5; ++u) { xr[u] = vx; yr[u] = vx; pr[u] = vx; }

    // prefetch step 0
    int r0 = o0; if (r0 > H - 1) r0 = H - 1;
    float4 xn1 = *(const float4*)(xb + r0 * W + col4);
    float4 yn1 = *(const float4*)(yb + r0 * W + col4);

    #pragma unroll 2
    for (int t = 0; t < NSTEP / 4; ++t) {
        #pragma unroll
        for (int u4 = 0; u4 < 4; ++u4) {
            const int s = t * 4 + u4;
            const int u = s % 5;               // ring slot (s in [0,24))

            const float4 xn = xn1;
            const float4 yn = yn1;

            // prefetch step s+1
            {
                int rn = o0 + s + 1; if (rn > H - 1) rn = H - 1;
                const int offn = rn * W + col4;
                xn1 = *(const float4*)(xb + offn);
                yn1 = *(const float4*)(yb + offn);
            }

            // vertical running 5-sums (rows s-4..s), ring replaces row s-5
            vx.x += xn.x - xr[u].x; vx.y += xn.y - xr[u].y;
            vx.z += xn.z - xr[u].z; vx.w += xn.w - xr[u].w;
            vy.x += yn.x - yr[u].x; vy.y += yn.y - yr[u].y;
            vy.z += yn.z - yr[u].z; vy.w += yn.w - yr[u].w;
            xr[u] = xn; yr[u] = yn;

            // horizontal 5-sums at this lane's 4 cols (neighbors via shfl)
            const float vxl0 = shfl_up1(vx.z), vxl1 = shfl_up1(vx.w);
            const float vxr0 = shfl_dn1(vx.x), vxr1 = shfl_dn1(vx.y);
            const float vyl0 = shfl_up1(vy.z), vyl1 = shfl_up1(vy.w);
            const float vyr0 = shfl_dn1(vy.x), vyr1 = shfl_dn1(vy.y);

            const float hx0 = vxl0 + vxl1 + vx.x + vx.y + vx.z;
            const float hx1 = hx0 - vxl0 + vx.w;
            const float hx2 = hx1 - vxl1 + vxr0;
            const float hx3 = hx2 - vx.x + vxr1;
            const float hy0 = vyl0 + vyl1 + vy.x + vy.y + vy.z;
            const float hy1 = hy0 - vyl0 + vy.w;
            const float hy2 = hy1 - vyl1 + vyr0;
            const float hy3 = hy2 - vy.x + vyr1;

            // centers: row r-2 = ring slot (u+3)%5
            const float4 cx4 = xr[(u + 3) % 5];
            const float4 cy4 = yr[(u + 3) % 5];

            float4 p;
            p.x = (cx4.x - hx0 * inv25) * (cy4.x - hy0 * inv25);
            p.y = (cx4.y - hx1 * inv25) * (cy4.y - hy1 * inv25);
            p.z = (cx4.z - hx2 * inv25) * (cy4.z - hy2 * inv25);
            p.w = (cx4.w - hx3 * inv25) * (cy4.w - hy3 * inv25);

            // vertical running 5-sum of p
            vp.x += p.x - pr[u].x; vp.y += p.y - pr[u].y;
            vp.z += p.z - pr[u].z; vp.w += p.w - pr[u].w;
            pr[u] = p;

            const int i = o0 + s - 8;          // output row
            if (s >= 8 && i < OH) {            // wave-uniform condition
                const float vpl0 = shfl_up1(vp.z), vpl1 = shfl_up1(vp.w);
                const float vpr0 = shfl_dn1(vp.x), vpr1 = shfl_dn1(vp.y);
                const float h0 = vpl0 + vpl1 + vp.x + vp.y + vp.z;
                const float h1 = h0 - vpl0 + vp.w;
                const float h2 = h1 - vpl1 + vpr0;
                const float h3 = h2 - vp.x + vpr1;
                if (lane_ok) {
                    float4 o4 = make_float4(h0 * inv25, h1 * inv25,
                                            h2 * inv25, h3 * inv25);
                    *(float4*)(ob + (size_t)i * OW + j4) = o4;
                }
            }
        }
    }
}

extern "C" void kernel_launch(void* const* d_in, const int* in_sizes, int n_in,
                              void* d_out, int out_size, void* d_ws, size_t ws_size,
                              hipStream_t stream) {
    const float* x = (const float*)d_in[0];
    const float* y = (const float*)d_in[1];
    // d_in[2]/d_in[3]: constant conv masks (1/25 box, center impulse) — baked in.
    float* out = (float*)d_out;

    // 16 batch x 5 strips x 64 row-chunks = 5120 wave-jobs = 1280 blocks x 4 waves
    dim3 grid(NBATCH * NSTRIP * NCHUNK / 4);
    dim3 block(256);
    hipLaunchKernelGGL(cov_kernel, grid, block, 0, stream, x, y, out);
}

// Round 4
// 190.145 us; speedup vs baseline: 1.5303x; 1.5303x over previous
//
#include <hip/hip_runtime.h>

// CovarianceLayer: out = boxmean5x5( (center(x)-boxmean5x5(x)) * (center(y)-boxmean5x5(y)) )
// x,y: [16,1,1024,1024] fp32; out: [16,1,1016,1016] fp32.
//
// Register-resident vertical scan (no LDS, no barriers).
// R4 = R2 structure (inner unroll of 5 => ring indices STATIC; R3's s%5 with a
// non-multiple unroll caused dynamic indexing -> scratch spill -> 354MB writes)
// + occupancy fix: RCHUNK 32->17 (NSTEP=25, still /5) => 4800 wave-jobs
// (~18.75 waves/CU vs 10) + next-row prefetch kept from R3.

#define W 1024
#define H 1024
#define OW 1016
#define OH 1016
#define NBATCH 16
#define NSTRIP 5
#define NCHUNK 60
#define RCHUNK 17
#define NSTEP (RCHUNK + 8)    // 25 input rows per job
#define STRIP_OUT 248

__device__ __forceinline__ float shfl_up1(float v) { return __shfl_up(v, 1, 64); }
__device__ __forceinline__ float shfl_dn1(float v) { return __shfl_down(v, 1, 64); }

__global__ __launch_bounds__(256) void cov_kernel(
    const float* __restrict__ x, const float* __restrict__ y,
    float* __restrict__ out)
{
    const int wid  = (blockIdx.x << 2) + (threadIdx.x >> 6);
    const int lane = threadIdx.x & 63;

    // job decode: chunk fastest (adjacent waves share row halo in cache)
    const int chunk = wid % NCHUNK;
    const int rest  = wid / NCHUNK;
    const int strip = rest % NSTRIP;
    const int batch = rest / NSTRIP;

    const int o0   = chunk * RCHUNK;      // first output row of this job
    const int base = strip * STRIP_OUT;   // first input col of this strip

    int col4 = base + (lane << 2);
    if (col4 > W - 4) col4 = W - 4;       // clamp (strip 4 tail lanes; masked below)

    const float* __restrict__ xb = x + (size_t)batch * H * W;
    const float* __restrict__ yb = y + (size_t)batch * H * W;
    float* __restrict__ ob = out + (size_t)batch * OH * OW;

    const int j4 = base + ((lane - 1) << 2);   // first output col this lane stores
    const bool lane_ok = (lane >= 1) && (lane <= 62) && (j4 <= OW - 4);

    constexpr float inv25 = 1.0f / 25.0f;

    float4 xr[5], yr[5], pr[5];
    float4 vx = make_float4(0.f, 0.f, 0.f, 0.f);
    float4 vy = vx, vp = vx;
    #pragma unroll
    for (int u = 0; u < 5; ++u) { xr[u] = vx; yr[u] = vx; pr[u] = vx; }

    // prefetch step 0
    {
        int r0 = o0; if (r0 > H - 1) r0 = H - 1;
        xr[4] = *(const float4*)(xb + r0 * W + col4);   // holds "next" at loop top,
        yr[4] = *(const float4*)(yb + r0 * W + col4);   // see swap below
    }
    float4 xn1 = xr[4], yn1 = yr[4];
    xr[4] = make_float4(0.f, 0.f, 0.f, 0.f);
    yr[4] = xr[4];

    for (int t = 0; t < NSTEP / 5; ++t) {
        #pragma unroll
        for (int u = 0; u < 5; ++u) {          // u IS the ring slot: static indices
            const int s = t * 5 + u;

            const float4 xn = xn1;
            const float4 yn = yn1;

            // prefetch step s+1 (kept simple & static; last iter reloads row H-1)
            {
                int rn = o0 + s + 1; if (rn > H - 1) rn = H - 1;
                const int offn = rn * W + col4;
                xn1 = *(const float4*)(xb + offn);
                yn1 = *(const float4*)(yb + offn);
            }

            // vertical running 5-sums (rows s-4..s), ring replaces row s-5
            vx.x += xn.x - xr[u].x; vx.y += xn.y - xr[u].y;
            vx.z += xn.z - xr[u].z; vx.w += xn.w - xr[u].w;
            vy.x += yn.x - yr[u].x; vy.y += yn.y - yr[u].y;
            vy.z += yn.z - yr[u].z; vy.w += yn.w - yr[u].w;
            xr[u] = xn; yr[u] = yn;

            // horizontal 5-sums at this lane's 4 cols (neighbors via shfl)
            const float vxl0 = shfl_up1(vx.z), vxl1 = shfl_up1(vx.w);
            const float vxr0 = shfl_dn1(vx.x), vxr1 = shfl_dn1(vx.y);
            const float vyl0 = shfl_up1(vy.z), vyl1 = shfl_up1(vy.w);
            const float vyr0 = shfl_dn1(vy.x), vyr1 = shfl_dn1(vy.y);

            const float hx0 = vxl0 + vxl1 + vx.x + vx.y + vx.z;
            const float hx1 = hx0 - vxl0 + vx.w;
            const float hx2 = hx1 - vxl1 + vxr0;
            const float hx3 = hx2 - vx.x + vxr1;
            const float hy0 = vyl0 + vyl1 + vy.x + vy.y + vy.z;
            const float hy1 = hy0 - vyl0 + vy.w;
            const float hy2 = hy1 - vyl1 + vyr0;
            const float hy3 = hy2 - vy.x + vyr1;

            // centers: row r-2 = ring slot (u+3)%5 — STATIC since u is literal
            const float4 cx4 = xr[(u + 3) % 5];
            const float4 cy4 = yr[(u + 3) % 5];

            float4 p;
            p.x = (cx4.x - hx0 * inv25) * (cy4.x - hy0 * inv25);
            p.y = (cx4.y - hx1 * inv25) * (cy4.y - hy1 * inv25);
            p.z = (cx4.z - hx2 * inv25) * (cy4.z - hy2 * inv25);
            p.w = (cx4.w - hx3 * inv25) * (cy4.w - hy3 * inv25);

            // vertical running 5-sum of p
            vp.x += p.x - pr[u].x; vp.y += p.y - pr[u].y;
            vp.z += p.z - pr[u].z; vp.w += p.w - pr[u].w;
            pr[u] = p;

            const int i = o0 + s - 8;          // output row
            if (s >= 8 && i < OH) {            // wave-uniform condition
                const float vpl0 = shfl_up1(vp.z), vpl1 = shfl_up1(vp.w);
                const float vpr0 = shfl_dn1(vp.x), vpr1 = shfl_dn1(vp.y);
                const float h0 = vpl0 + vpl1 + vp.x + vp.y + vp.z;
                const float h1 = h0 - vpl0 + vp.w;
                const float h2 = h1 - vpl1 + vpr0;
                const float h3 = h2 - vp.x + vpr1;
                if (lane_ok) {
                    float4 o4 = make_float4(h0 * inv25, h1 * inv25,
                                            h2 * inv25, h3 * inv25);
                    *(float4*)(ob + (size_t)i * OW + j4) = o4;
                }
            }
        }
    }
}

extern "C" void kernel_launch(void* const* d_in, const int* in_sizes, int n_in,
                              void* d_out, int out_size, void* d_ws, size_t ws_size,
                              hipStream_t stream) {
    const float* x = (const float*)d_in[0];
    const float* y = (const float*)d_in[1];
    // d_in[2]/d_in[3]: constant conv masks (1/25 box, center impulse) — baked in.
    float* out = (float*)d_out;

    // 16 batch x 5 strips x 60 row-chunks = 4800 wave-jobs = 1200 blocks x 4 waves
    dim3 grid(NBATCH * NSTRIP * NCHUNK / 4);
    dim3 block(256);
    hipLaunchKernelGGL(cov_kernel, grid, block, 0, stream, x, y, out);
}